// Round 1
// 222.507 us; speedup vs baseline: 1.0218x; 1.0218x over previous
//
#include <hip/hip_runtime.h>
#include <hip/hip_bf16.h>
#include <math.h>

#define NDIM 256
#define NROT 32640          // C(256,2)
#define NSEG 64
#define SEGLEN 510          // 64 * 510 == 32640 exactly
#define MATE (NDIM * NDIM)  // elements per plane
#define NODEE (2 * MATE)    // node = hi plane + lo plane (bf16 each)

typedef __bf16 bf16x4_t __attribute__((ext_vector_type(4)));
typedef __bf16 bf16x8_t __attribute__((ext_vector_type(8)));
typedef float f32x4_t __attribute__((ext_vector_type(4)));

// ---------------------------------------------------------------------------
// K2 (rewritten for latency): build 64 segment products (510 rotations each)
// applied to I, fp32 in LDS.
// Layout change: tile[rowblk][thread][8] -> each thread's 8-row chunk is
// contiguous, so row streaming is ds_read_b128/ds_write_b128 (2 ops per 8
// rows) instead of 8 strided b32 ops. 16-rotation batches with explicit A/B
// register double-buffering (unrolled x2, no rotating-array copies).
// Output: bf16 hi/lo planes. even seg -> TRANSPOSED ([c][k]), odd -> plain.
// ---------------------------------------------------------------------------

#define ROT1(RJ, CS) { float nri_ = fmaf((CS).x, ri, -((CS).y * (RJ))); \
                       (RJ) = fmaf((CS).y, ri, (CS).x * (RJ)); ri = nri_; }

#define LOAD16(P, JB, KK) \
    P##0 = *(const f32x4_t*)&tile[(JB)][t][0]; \
    P##1 = *(const f32x4_t*)&tile[(JB)][t][4]; \
    P##2 = *(const f32x4_t*)&tile[(JB) + 1][t][0]; \
    P##3 = *(const f32x4_t*)&tile[(JB) + 1][t][4]; \
    _Pragma("unroll") \
    for (int u = 0; u < 16; u++) P##c[u] = csl[(KK) + u];

#define COMP16(P, JB) \
    _Pragma("unroll") \
    for (int u = 0; u < 4; u++) ROT1(P##0[u], P##c[u]) \
    _Pragma("unroll") \
    for (int u = 0; u < 4; u++) ROT1(P##1[u], P##c[4 + u]) \
    _Pragma("unroll") \
    for (int u = 0; u < 4; u++) ROT1(P##2[u], P##c[8 + u]) \
    _Pragma("unroll") \
    for (int u = 0; u < 4; u++) ROT1(P##3[u], P##c[12 + u]) \
    *(f32x4_t*)&tile[(JB)][t][0] = P##0; \
    *(f32x4_t*)&tile[(JB)][t][4] = P##1; \
    *(f32x4_t*)&tile[(JB) + 1][t][0] = P##2; \
    *(f32x4_t*)&tile[(JB) + 1][t][4] = P##3;

__global__ __launch_bounds__(64, 1) void k_build(const float* __restrict__ rots,
                                                 __bf16* __restrict__ leaves) {
    __shared__ float tile[32][64][8];      // 64 KiB: row r at tile[r>>3][t][r&7]
    __shared__ float2 csl[SEGLEN + 16];
    const int t = threadIdx.x;             // 0..63
    const int seg = blockIdx.x >> 2;
    const int cg = blockIdx.x & 3;
    const int col = cg * 64 + t;
    const int kg0 = seg * SEGLEN;

    // fused sincos: stage this segment's (c,s) into LDS
    for (int u = t; u < SEGLEN; u += 64) {
        float th = rots[kg0 + u];
        float s, c;
        sincosf(th, &s, &c);
        csl[u] = make_float2(c, s);
    }
    for (int u = SEGLEN + t; u < SEGLEN + 16; u += 64) csl[u] = make_float2(1.f, 0.f);

    // init: identity columns for this column group (b128 writes)
    #pragma unroll
    for (int jb = 0; jb < 32; jb++) {
        f32x4_t z0 = {0.f, 0.f, 0.f, 0.f}, z1 = {0.f, 0.f, 0.f, 0.f};
        if ((col >> 3) == jb) {
            if ((col & 7) < 4) z0[col & 3] = 1.0f;
            else               z1[col & 3] = 1.0f;
        }
        *(f32x4_t*)&tile[jb][t][0] = z0;
        *(f32x4_t*)&tile[jb][t][4] = z1;
    }
    // single wave: LDS ops execute in order, no barrier needed

    int k = 0;
    int i = 0, cum = 0;
    while (cum + (NDIM - 1 - i) <= kg0) { cum += NDIM - 1 - i; i++; }
    int j = i + 1 + (kg0 - cum);

    float* T = &tile[0][0][0];
    #define TADDR(r) ((((r) >> 3) * 512) + t * 8 + ((r) & 7))

    while (k < SEGLEN) {
        float ri = T[TADDR(i)];
        int rem = min(NDIM - j, SEGLEN - k);

        // scalar peel to 8-row alignment
        int npeel = min((8 - (j & 7)) & 7, rem);
        for (int u = 0; u < npeel; u++) {
            float2 cs = csl[k];
            float rj = T[TADDR(j)];
            float nri = fmaf(cs.x, ri, -(cs.y * rj));
            T[TADDR(j)] = fmaf(cs.y, ri, cs.x * rj);
            ri = nri; j++; k++;
        }
        rem -= npeel;

        // 16-rotation batches, A/B double-buffered register prefetch
        if (rem >= 16) {
            int jb = j >> 3;
            f32x4_t A0, A1, A2, A3, B0, B1, B2, B3;
            float2 Ac[16], Bc[16];
            LOAD16(A, jb, k)
            while (rem >= 48) {
                LOAD16(B, jb + 2, k + 16)
                COMP16(A, jb)
                jb += 2; j += 16; k += 16; rem -= 16;
                LOAD16(A, jb + 2, k + 16)
                COMP16(B, jb)
                jb += 2; j += 16; k += 16; rem -= 16;
            }
            if (rem >= 32) {
                LOAD16(B, jb + 2, k + 16)
                COMP16(A, jb)
                jb += 2; j += 16; k += 16; rem -= 16;
                COMP16(B, jb)
                jb += 2; j += 16; k += 16; rem -= 16;
            } else {
                COMP16(A, jb)
                jb += 2; j += 16; k += 16; rem -= 16;
            }
        }

        // 8-rotation cleanup batch
        if (rem >= 8) {
            int jb = j >> 3;
            f32x4_t a0 = *(const f32x4_t*)&tile[jb][t][0];
            f32x4_t a1 = *(const f32x4_t*)&tile[jb][t][4];
            float2 cc[8];
            #pragma unroll
            for (int u = 0; u < 8; u++) cc[u] = csl[k + u];
            #pragma unroll
            for (int u = 0; u < 4; u++) ROT1(a0[u], cc[u])
            #pragma unroll
            for (int u = 0; u < 4; u++) ROT1(a1[u], cc[4 + u])
            *(f32x4_t*)&tile[jb][t][0] = a0;
            *(f32x4_t*)&tile[jb][t][4] = a1;
            j += 8; k += 8; rem -= 8;
        }

        // scalar tail
        while (rem > 0) {
            float2 cs = csl[k];
            float rj = T[TADDR(j)];
            float nri = fmaf(cs.x, ri, -(cs.y * rj));
            T[TADDR(j)] = fmaf(cs.y, ri, cs.x * rj);
            ri = nri; j++; k++; rem--;
        }

        T[TADDR(i)] = ri;
        if (j == NDIM) { i++; j = i + 1; }
    }
    #undef TADDR

    __bf16* hi = leaves + (size_t)seg * NODEE;
    __bf16* lo = hi + MATE;
    if (seg & 1) {
        // plain [r][col]: scalar 2B stores, coalesced across lanes
        for (int jb = 0; jb < 32; jb++) {
            f32x4_t v0 = *(const f32x4_t*)&tile[jb][t][0];
            f32x4_t v1 = *(const f32x4_t*)&tile[jb][t][4];
            #pragma unroll
            for (int u = 0; u < 8; u++) {
                float v = (u < 4) ? v0[u & 3] : v1[u & 3];
                __bf16 h = (__bf16)v;
                hi[(size_t)(jb * 8 + u) * NDIM + col] = h;
                lo[(size_t)(jb * 8 + u) * NDIM + col] = (__bf16)(v - (float)h);
            }
        }
    } else {
        // transposed [c][k]: contiguous bf16x8 stores per thread-row
        for (int jb = 0; jb < 32; jb++) {
            f32x4_t v0 = *(const f32x4_t*)&tile[jb][t][0];
            f32x4_t v1 = *(const f32x4_t*)&tile[jb][t][4];
            bf16x8_t vh, vl;
            #pragma unroll
            for (int u = 0; u < 8; u++) {
                float v = (u < 4) ? v0[u & 3] : v1[u & 3];
                __bf16 h = (__bf16)v;
                vh[u] = h;
                vl[u] = (__bf16)(v - (float)h);
            }
            *(bf16x8_t*)&hi[(size_t)col * NDIM + jb * 8] = vh;
            *(bf16x8_t*)&lo[(size_t)col * NDIM + jb * 8] = vl;
        }
    }
}

// ---------------------------------------------------------------------------
// K3: one-shot tree combine. node[p] = child[2p+1] @ child[2p].
// Children as bf16 hi/lo planes; child[2p] transposed ([c][k]), child[2p+1]
// plain ([r][k]).  C ~= Bh@Ah + Bh@Al + Bl@Ah (fp32 acc).
// Block = 64x64 output over FULL K=256: stage 4 plane-tiles (132 KB LDS),
// ONE barrier, 96 MFMAs, store hi/lo (transposed if !final && p even).
// Grid = npairs*16, 256 threads (4 waves 2x2 of 32x32).
// ---------------------------------------------------------------------------
#define LDK 264   // padded LDS row (bf16); 528 B, 16B-aligned, bank-rotating
__global__ __launch_bounds__(256) void k_combine(const __bf16* __restrict__ src,
                                                 __bf16* __restrict__ dst,
                                                 int finalLevel) {
    __shared__ __bf16 planes[4][64 * LDK];   // Bhi, Blo, Ahi, Alo

    const int p = blockIdx.x >> 4;
    const int qd = blockIdx.x & 15;
    const int rbq = (qd >> 2) * 64;   // output row base (B rows)
    const int cbq = (qd & 3) * 64;    // output col base (A rows, transposed)
    const __bf16* A = src + (size_t)(2 * p) * NODEE;       // transposed child
    const __bf16* B = src + (size_t)(2 * p + 1) * NODEE;   // plain child
    __bf16* Chi = dst + (size_t)p * NODEE;
    __bf16* Clo = Chi + MATE;
    const bool storeT = (!finalLevel) && ((p & 1) == 0);

    const int t = threadIdx.x;
    const int wid = t >> 6, lane = t & 63;
    const int wr2 = (wid >> 1) * 32, wc2 = (wid & 1) * 32;
    const int lrow = lane & 15, kg = lane >> 4;

    const __bf16* plane_src[4] = {B, B + MATE, A, A + MATE};
    const int plane_row0[4] = {rbq, rbq, cbq, cbq};
    #pragma unroll
    for (int q = 0; q < 32; q++) {
        int g = q * 256 + t;
        int pl = g >> 11;            // 2048 16B-chunks per plane
        int c = g & 2047;
        int row = c >> 5, sg = c & 31;
        bf16x8_t v = *(const bf16x8_t*)&plane_src[pl][(size_t)(plane_row0[pl] + row) * NDIM + sg * 8];
        *(bf16x8_t*)&planes[pl][row * LDK + sg * 8] = v;
    }
    __syncthreads();

    f32x4_t acc[2][2] = {};
    #pragma unroll
    for (int kc = 0; kc < 8; kc++) {
        bf16x8_t afh[2], afl[2], bfh[2], bfl[2];
        #pragma unroll
        for (int mt = 0; mt < 2; mt++) {
            int r = (wr2 + mt * 16 + lrow) * LDK + kc * 32 + kg * 8;
            afh[mt] = *(const bf16x8_t*)&planes[0][r];
            afl[mt] = *(const bf16x8_t*)&planes[1][r];
        }
        #pragma unroll
        for (int nt = 0; nt < 2; nt++) {
            int r = (wc2 + nt * 16 + lrow) * LDK + kc * 32 + kg * 8;
            bfh[nt] = *(const bf16x8_t*)&planes[2][r];
            bfl[nt] = *(const bf16x8_t*)&planes[3][r];
        }
        #pragma unroll
        for (int mt = 0; mt < 2; mt++)
            #pragma unroll
            for (int nt = 0; nt < 2; nt++) {
                acc[mt][nt] = __builtin_amdgcn_mfma_f32_16x16x32_bf16(afh[mt], bfh[nt], acc[mt][nt], 0, 0, 0);
                acc[mt][nt] = __builtin_amdgcn_mfma_f32_16x16x32_bf16(afh[mt], bfl[nt], acc[mt][nt], 0, 0, 0);
                acc[mt][nt] = __builtin_amdgcn_mfma_f32_16x16x32_bf16(afl[mt], bfh[nt], acc[mt][nt], 0, 0, 0);
            }
    }

    // C/D: col = lane&15, row = (lane>>4)*4 + reg
    #pragma unroll
    for (int mt = 0; mt < 2; mt++)
        #pragma unroll
        for (int nt = 0; nt < 2; nt++) {
            int grow = rbq + wr2 + mt * 16 + kg * 4;
            int gcol = cbq + wc2 + nt * 16 + lrow;
            if (storeT) {
                bf16x4_t vh, vl;
                #pragma unroll
                for (int r = 0; r < 4; r++) {
                    float v = acc[mt][nt][r];
                    __bf16 h = (__bf16)v;
                    vh[r] = h;
                    vl[r] = (__bf16)(v - (float)h);
                }
                *(bf16x4_t*)&Chi[(size_t)gcol * NDIM + grow] = vh;
                *(bf16x4_t*)&Clo[(size_t)gcol * NDIM + grow] = vl;
            } else if (finalLevel) {
                #pragma unroll
                for (int r = 0; r < 4; r++)
                    Chi[(size_t)(grow + r) * NDIM + gcol] = (__bf16)acc[mt][nt][r];
            } else {
                #pragma unroll
                for (int r = 0; r < 4; r++) {
                    float v = acc[mt][nt][r];
                    __bf16 h = (__bf16)v;
                    Chi[(size_t)(grow + r) * NDIM + gcol] = h;
                    Clo[(size_t)(grow + r) * NDIM + gcol] = (__bf16)(v - (float)h);
                }
            }
        }
}

// ---------------------------------------------------------------------------
// K4: Y[b][c] = sum_k X[b][k] * Mhi[c][k]; Mhi bf16 row-major (root hi plane).
// BM=BN=128, BK=64 (4 iters), register prefetch of iter+1 global loads,
// 4 waves 2x2 of 64x64, LDS 36 KB.
// ---------------------------------------------------------------------------
#define LDA 72    // padded LDS row (bf16), 144 B
__global__ __launch_bounds__(256, 2) void k_gemm(const float* __restrict__ X,
                                                 const __bf16* __restrict__ Mhi,
                                                 float* __restrict__ Y) {
    __shared__ __bf16 As[128 * LDA];
    __shared__ __bf16 Bs[128 * LDA];
    const int bx = blockIdx.x;
    const int xcd = bx & 7;
    const int q = bx >> 3;
    const int bn = (q & 1) * 128;
    const int bm = (xcd + (q >> 1) * 8) * 128;
    const int t = threadIdx.x;
    const int wid = t >> 6;
    const int lane = t & 63;
    const int wr = (wid >> 1) * 64;
    const int wc = (wid & 1) * 64;
    const int lrow = lane & 15;
    const int kg = lane >> 4;

    f32x4_t acc[4][4] = {};

    f32x4_t ra[8];
    bf16x8_t rb[4];

    // prologue: load iter 0
    #pragma unroll
    for (int qq = 0; qq < 8; qq++) {
        int g = qq * 256 + t;
        ra[qq] = *(const f32x4_t*)&X[(size_t)(bm + (g >> 4)) * 256 + (g & 15) * 4];
    }
    #pragma unroll
    for (int qq = 0; qq < 4; qq++) {
        int g = qq * 256 + t;
        rb[qq] = *(const bf16x8_t*)&Mhi[(size_t)(bn + (g >> 3)) * 256 + (g & 7) * 8];
    }

    #pragma unroll
    for (int it = 0; it < 4; it++) {
        #pragma unroll
        for (int qq = 0; qq < 8; qq++) {
            int g = qq * 256 + t;
            f32x4_t v = ra[qq];
            bf16x4_t h = {(__bf16)v.x, (__bf16)v.y, (__bf16)v.z, (__bf16)v.w};
            *(bf16x4_t*)&As[(g >> 4) * LDA + (g & 15) * 4] = h;
        }
        #pragma unroll
        for (int qq = 0; qq < 4; qq++) {
            int g = qq * 256 + t;
            *(bf16x8_t*)&Bs[(g >> 3) * LDA + (g & 7) * 8] = rb[qq];
        }
        __syncthreads();

        if (it < 3) {
            int kc = (it + 1) * 64;
            #pragma unroll
            for (int qq = 0; qq < 8; qq++) {
                int g = qq * 256 + t;
                ra[qq] = *(const f32x4_t*)&X[(size_t)(bm + (g >> 4)) * 256 + kc + (g & 15) * 4];
            }
            #pragma unroll
            for (int qq = 0; qq < 4; qq++) {
                int g = qq * 256 + t;
                rb[qq] = *(const bf16x8_t*)&Mhi[(size_t)(bn + (g >> 3)) * 256 + kc + (g & 7) * 8];
            }
        }

        #pragma unroll
        for (int k2 = 0; k2 < 2; k2++) {
            bf16x8_t af[4], bfr[4];
            #pragma unroll
            for (int mt = 0; mt < 4; mt++)
                af[mt] = *(const bf16x8_t*)&As[(wr + mt * 16 + lrow) * LDA + k2 * 32 + kg * 8];
            #pragma unroll
            for (int nt = 0; nt < 4; nt++)
                bfr[nt] = *(const bf16x8_t*)&Bs[(wc + nt * 16 + lrow) * LDA + k2 * 32 + kg * 8];
            #pragma unroll
            for (int mt = 0; mt < 4; mt++)
                #pragma unroll
                for (int nt = 0; nt < 4; nt++)
                    acc[mt][nt] = __builtin_amdgcn_mfma_f32_16x16x32_bf16(af[mt], bfr[nt], acc[mt][nt], 0, 0, 0);
        }
        __syncthreads();
    }

    const int ocol = bn + wc + lrow;
    const int orow = bm + wr + kg * 4;
    #pragma unroll
    for (int mt = 0; mt < 4; mt++)
        #pragma unroll
        for (int nt = 0; nt < 4; nt++)
            #pragma unroll
            for (int r = 0; r < 4; r++)
                Y[(size_t)(orow + mt * 16 + r) * 256 + ocol + nt * 16] = acc[mt][nt][r];
}

// ---------------------------------------------------------------------------
// workspace: B0 = 64 nodes x 256 KB = 16 MB; B1 = 32 nodes x 256 KB = 8 MB.
// tree: B0(64) ->B1(32) ->B0(16) ->B1(8) ->B0(4) ->B1(2) ->B0(1=root, hi only)
// ---------------------------------------------------------------------------
extern "C" void kernel_launch(void* const* d_in, const int* in_sizes, int n_in,
                              void* d_out, int out_size, void* d_ws, size_t ws_size,
                              hipStream_t stream) {
    const float* x = (const float*)d_in[0];
    const float* rots = (const float*)d_in[1];
    float* out = (float*)d_out;

    __bf16* B0 = (__bf16*)d_ws;
    __bf16* B1 = B0 + (size_t)NSEG * NODEE;

    k_build<<<NSEG * 4, 64, 0, stream>>>(rots, B0);
    k_combine<<<32 * 16, 256, 0, stream>>>(B0, B1, 0);
    k_combine<<<16 * 16, 256, 0, stream>>>(B1, B0, 0);
    k_combine<<<8 * 16, 256, 0, stream>>>(B0, B1, 0);
    k_combine<<<4 * 16, 256, 0, stream>>>(B1, B0, 0);
    k_combine<<<2 * 16, 256, 0, stream>>>(B0, B1, 0);
    k_combine<<<1 * 16, 256, 0, stream>>>(B1, B0, 1);
    k_gemm<<<1024, 256, 0, stream>>>(x, B0, out);
}